// Round 21
// baseline (3865.488 us; speedup 1.0000x reference)
//
#include <hip/hip_runtime.h>
#include <math.h>

#define NS0 80000
#define NS1 60000
#define NS2 30000
#define NTOT 170000
#define OFF1 80000
#define OFF2 140000

// bulk scratch as device global (harness ws_size too small; allocated at module load)
__device__ float g_ws[372000000];  // ~1.49 GB

typedef __attribute__((ext_vector_type(8))) short bf16x8;
typedef __attribute__((ext_vector_type(4))) float f32x4;

__device__ inline float gelu_f(float x) {
  float x3 = x * x * x;
  return 0.5f * x * (1.0f + tanhf(0.7978845608028654f * (x + 0.044715f * x3)));
}
__device__ inline ushort f2bf(float f) {
  unsigned u = __float_as_uint(f);
  unsigned r = (u + 0x7FFFu + ((u >> 16) & 1u)) >> 16;
  return (ushort)r;
}
__device__ inline float bf2f(ushort u) { return __uint_as_float((unsigned)u << 16); }
__device__ inline float bfu2f(unsigned u16) { return __uint_as_float(u16 << 16); }

// ---- segmented bf16 MFMA GEMM (up to 4 segments) ----
// R17 config: tile 64x128, 4 waves (2x2, each 32x64), BK=32, double-buffered
// LDS prefetch-before-compute, 24KB LDS, XCD-chunked 1D grid.
struct Segs {
  int n, ncb;
  int cum[5];
  int m[4];
  long long aoff[4], woff[4], coff[4], shoff[4];
  int bo[4], skidx[4];
};

__global__ __launch_bounds__(256) void gemm_seg(
    const ushort* __restrict__ A, int lda,
    const ushort* __restrict__ W, int ldb,
    const float* __restrict__ biasBase,
    float* __restrict__ CfBase, int ldc,
    ushort* __restrict__ CbBase, int ldcb,
    int K, Segs segs,
    const ushort* __restrict__ skHBase, int ldsk,
    const float* __restrict__ skvBase)
{
  __shared__ __align__(16) ushort smem[12288];   // 24 KB: staging; epilogue reuses 16 KB
  ushort* Asl = smem;            // 2 bufs x 2048 (64 rows x 32)
  ushort* Bsl = smem + 4096;     // 2 bufs x 4096 (128 rows x 32)

  int total = segs.cum[segs.n] * segs.ncb;
  int b = blockIdx.x;
  int q = total >> 3, r = total & 7;
  int xcd = b & 7, rank = b >> 3;
  int base = (xcd < r) ? xcd * (q + 1) : r * (q + 1) + (xcd - r) * q;
  int work = base + rank;
  int rb = work / segs.ncb;
  int cb = work - rb * segs.ncb;
  int t = 0;
  while (t + 1 < segs.n && rb >= segs.cum[t + 1]) ++t;
  const int row0 = (rb - segs.cum[t]) * 64;
  const int col0 = cb * 128;
  const int M = segs.m[t];
  const ushort* Aseg = A + segs.aoff[t];
  const ushort* Wseg = W + segs.woff[t];

  const int tid = threadIdx.x;
  const int w = tid >> 6, l = tid & 63;
  const int wr = (w >> 1) * 32, wc = (w & 1) * 64;
  const int lr = l >> 2;
  const int lk = (l & 3) * 8;
  const int fr = l & 15;
  const int fk = (l >> 4) * 8;

  f32x4 acc[2][4];
#pragma unroll
  for (int i = 0; i < 2; ++i)
#pragma unroll
    for (int j = 0; j < 4; ++j) acc[i][j] = (f32x4){0.f, 0.f, 0.f, 0.f};

  auto stage = [&](int buf, int k0) {
    {
      const ushort* ga = Aseg + (size_t)(row0 + w * 16 + lr) * lda + k0 + lk;
      __builtin_amdgcn_global_load_lds(
          (const __attribute__((address_space(1))) void*)ga,
          (__attribute__((address_space(3))) void*)&Asl[buf * 2048 + w * 512], 16, 0, 0);
    }
#pragma unroll
    for (int ci = 0; ci < 2; ++ci) {
      int chunk = w * 2 + ci;
      const ushort* gb = Wseg + (size_t)(col0 + chunk * 16 + lr) * ldb + k0 + lk;
      __builtin_amdgcn_global_load_lds(
          (const __attribute__((address_space(1))) void*)gb,
          (__attribute__((address_space(3))) void*)&Bsl[buf * 4096 + chunk * 512], 16, 0, 0);
    }
  };

  const int nk = K >> 5;
  stage(0, 0);
  __syncthreads();
  int cur = 0;
  for (int tt = 0; tt < nk; ++tt) {
    if (tt + 1 < nk) stage(cur ^ 1, (tt + 1) << 5);
    bf16x8 af[2], bfr[4];
#pragma unroll
    for (int i = 0; i < 2; ++i)
      af[i] = *(const bf16x8*)&Asl[cur * 2048 + (wr + i * 16 + fr) * 32 + fk];
#pragma unroll
    for (int j = 0; j < 4; ++j)
      bfr[j] = *(const bf16x8*)&Bsl[cur * 4096 + (wc + j * 16 + fr) * 32 + fk];
#pragma unroll
    for (int i = 0; i < 2; ++i)
#pragma unroll
      for (int j = 0; j < 4; ++j)
        acc[i][j] = __builtin_amdgcn_mfma_f32_16x16x32_bf16(af[i], bfr[j], acc[i][j], 0, 0, 0);
    __syncthreads();
    cur ^= 1;
  }

  const ushort* skH = skHBase ? skHBase + segs.shoff[t] : nullptr;
  float al = 0.f;
  if (skH) al = 1.f / (1.f + __expf(-skvBase[segs.skidx[t]]));
  float* Cf = CfBase ? CfBase + segs.coff[t] : nullptr;
  ushort* Cb = CbBase ? CbBase + segs.coff[t] : nullptr;
  const float* bias = biasBase ? biasBase + segs.bo[t] : nullptr;

#pragma unroll
  for (int j = 0; j < 4; ++j) {
    int lcol = wc + j * 16 + fr;
    int col = col0 + lcol;
    float bv = bias ? bias[col] : 0.f;
#pragma unroll
    for (int i = 0; i < 2; ++i) {
      int lrbase = wr + i * 16 + (l >> 4) * 4;
#pragma unroll
      for (int r2 = 0; r2 < 4; ++r2) {
        int lrow = lrbase + r2;
        int row = row0 + lrow;
        if (row < M) {
          float v = acc[i][j][r2] + bv;
          if (skH) v = al * v + (1.f - al) * bf2f(skH[(size_t)row * ldsk + col]);
          if (Cf) Cf[(size_t)row * ldc + col] = v;
          if (Cb) smem[lrow * 128 + lcol] = f2bf(v);
        }
      }
    }
  }
  if (Cb) {
    __syncthreads();
#pragma unroll
    for (int it = 0; it < 4; ++it) {
      int lrow = it * 16 + (tid >> 4);
      int row = row0 + lrow;
      if (row < M) {
        int lc = (tid & 15) * 8;
        *(bf16x8*)(Cb + (size_t)row * ldcb + col0 + lc) =
            *(const bf16x8*)&smem[lrow * 128 + lc];
      }
    }
  }
}

// transpose f32 [K][N] -> bf16 [N][K], batched over blockIdx.z
__global__ __launch_bounds__(256) void wtrans(
    const float* __restrict__ src, ushort* __restrict__ dst, int K, int N)
{
  __shared__ float t[32][33];
  size_t zo = (size_t)blockIdx.z * K * N;
  int kb = blockIdx.x * 32, nb = blockIdx.y * 32;
  int tx = threadIdx.x & 31, ty = threadIdx.x >> 5;
#pragma unroll
  for (int r = 0; r < 32; r += 8) {
    int k = kb + ty + r, n = nb + tx;
    if (k < K && n < N) t[ty + r][tx] = src[zo + (size_t)k * N + n];
  }
  __syncthreads();
#pragma unroll
  for (int r = 0; r < 32; r += 8) {
    int n = nb + ty + r, k = kb + tx;
    if (n < N && k < K) dst[zo + (size_t)n * K + k] = f2bf(t[tx][ty + r]);
  }
}

__global__ __launch_bounds__(256) void wtrans_f32(
    const float* __restrict__ src, float* __restrict__ dst, int K, int N)
{
  __shared__ float t[32][33];
  int kb = blockIdx.x * 32, nb = blockIdx.y * 32;
  int tx = threadIdx.x & 31, ty = threadIdx.x >> 5;
#pragma unroll
  for (int r = 0; r < 32; r += 8) {
    int k = kb + ty + r, n = nb + tx;
    if (k < K && n < N) t[ty + r][tx] = src[(size_t)k * N + n];
  }
  __syncthreads();
#pragma unroll
  for (int r = 0; r < 32; r += 8) {
    int n = nb + ty + r, k = kb + tx;
    if (n < N && k < K) dst[(size_t)n * K + k] = t[tx][ty + r];
  }
}

__global__ void conv_bf16(const float* __restrict__ in, ushort* __restrict__ out, int n4) {
  int i = blockIdx.x * blockDim.x + threadIdx.x;
  if (i >= n4) return;
  float4 v = *(const float4*)(in + (size_t)i * 4);
  ushort4 o;
  o.x = f2bf(v.x); o.y = f2bf(v.y); o.z = f2bf(v.z); o.w = f2bf(v.w);
  *(ushort4*)(out + (size_t)i * 4) = o;
}

// combined rel bias: BCMB[(l,e)][0:256]=b_k@W_krel, [256:512]=b_v@W_vrel
__global__ __launch_bounds__(512) void bcomb_kernel(
    const float* __restrict__ b_kqv,
    const ushort* __restrict__ WT_krel, const ushort* __restrict__ WT_vrel,
    float* __restrict__ BCMB)
{
  int le = blockIdx.x;            // l*4+e
  int l = le >> 2, e = le & 3;
  int ti = (e == 0) ? 0 : (e == 1) ? 1 : (e == 2) ? 0 : 2;
  int j = threadIdx.x;
  const float* bb = b_kqv + ((size_t)l * 3 + ti) * 768 + ((j < 256) ? 0 : 512);
  const ushort* wrow = ((j < 256) ? WT_krel : WT_vrel) +
                       (size_t)le * 65536 + (size_t)(j & 255) * 256;
  float s = 0.f;
  for (int o2 = 0; o2 < 256; ++o2) s += bb[o2] * bf2f(wrow[o2]);
  BCMB[(size_t)le * 512 + j] = s;
}

// ---------------- LayerNorm: bf16 in (ld param), bf16 out ----------------
__global__ __launch_bounds__(256) void ln_kernel(
    const ushort* __restrict__ X, int ldx,
    const float* __restrict__ g, const float* __restrict__ b,
    ushort* __restrict__ Hbf)
{
  int w = (blockIdx.x * blockDim.x + threadIdx.x) >> 6;
  int lane = threadIdx.x & 63;
  if (w >= NTOT) return;
  int type = (w < NS0) ? 0 : (w < OFF2 ? 1 : 2);
  ushort4 xb = *(const ushort4*)(X + (size_t)w * ldx + (lane << 2));
  float x0 = bf2f(xb.x), x1 = bf2f(xb.y), x2 = bf2f(xb.z), x3 = bf2f(xb.w);
  float s = x0 + x1 + x2 + x3;
  float q = x0 * x0 + x1 * x1 + x2 * x2 + x3 * x3;
#pragma unroll
  for (int off = 32; off >= 1; off >>= 1) {
    s += __shfl_xor(s, off);
    q += __shfl_xor(q, off);
  }
  float m = s * (1.f / 256.f);
  float var = q * (1.f / 256.f) - m * m;
  float rs = rsqrtf(var + 1e-5f);
  float4 gg = *(const float4*)(g + type * 256 + (lane << 2));
  float4 bb = *(const float4*)(b + type * 256 + (lane << 2));
  ushort4 ob;
  ob.x = f2bf((x0 - m) * rs * gg.x + bb.x);
  ob.y = f2bf((x1 - m) * rs * gg.y + bb.y);
  ob.z = f2bf((x2 - m) * rs * gg.z + bb.z);
  ob.w = f2bf((x3 - m) * rs * gg.w + bb.w);
  *(ushort4*)(Hbf + (size_t)w * 256 + (lane << 2)) = ob;
}

// ---------------- CSR build ----------------
__global__ void csr_hist(const int* __restrict__ ei, int ne, int* __restrict__ deg) {
  int t = blockIdx.x * blockDim.x + threadIdx.x;
  if (t < ne) atomicAdd(&deg[ei[ne + t]], 1);
}
__global__ __launch_bounds__(256) void scan_block(
    const int* __restrict__ in, int n, int* __restrict__ out, int* __restrict__ bsum)
{
  __shared__ int sdata[256];
  int tid = threadIdx.x;
  int base = blockIdx.x * 1024 + tid * 4;
  int v[4]; int s = 0;
#pragma unroll
  for (int j = 0; j < 4; ++j) {
    int x = (base + j < n) ? in[base + j] : 0;
    v[j] = s; s += x;
  }
  sdata[tid] = s;
  __syncthreads();
  int own = s;
  for (int off = 1; off < 256; off <<= 1) {
    int u = (tid >= off) ? sdata[tid - off] : 0;
    __syncthreads();
    sdata[tid] += u;
    __syncthreads();
  }
  int thrExcl = sdata[tid] - own;
#pragma unroll
  for (int j = 0; j < 4; ++j)
    if (base + j < n) out[base + j] = thrExcl + v[j];
  if (tid == 255) bsum[blockIdx.x] = sdata[255];
}
__global__ void scan_bsum(int* __restrict__ bsum, int nb) {
  if (threadIdx.x == 0 && blockIdx.x == 0) {
    int r = 0;
    for (int b = 0; b < nb; ++b) { int t = bsum[b]; bsum[b] = r; r += t; }
    bsum[nb] = r;
  }
}
__global__ void scan_add(int* __restrict__ out, int n, const int* __restrict__ bsum, int nb) {
  int i = blockIdx.x * blockDim.x + threadIdx.x;
  if (i < n) out[i] += bsum[i >> 10];
  else if (i == n) out[n] = bsum[nb];
}
__global__ void csr_scatter(const int* __restrict__ ei, int ne,
                            const int* __restrict__ rowptr, int* __restrict__ cur,
                            int* __restrict__ src_csr, int* __restrict__ dst_csr) {
  int t = blockIdx.x * blockDim.x + threadIdx.x;
  if (t >= ne) return;
  int d = ei[ne + t];
  int pos = rowptr[d] + atomicAdd(&cur[d], 1);
  src_csr[pos] = ei[t];
  dst_csr[pos] = d;
}

// ---------------- edge scores: 2 edges per wave, 16B loads (raw scores) -------
__global__ __launch_bounds__(256) void edge_scores(
    const int* __restrict__ src_csr, const int* __restrict__ dst_csr, int ne,
    const ushort* __restrict__ Qb, int dst_off,
    const ushort* __restrict__ KR, int ldk,
    const float* __restrict__ prel,
    float* __restrict__ SC, size_t sc_off)
{
  int lane = threadIdx.x & 63;
  int sub = lane >> 5;
  int ln = lane & 31;
  int p = ((blockIdx.x * blockDim.x + threadIdx.x) >> 6) * 2 + sub;
  if (p >= ne) return;
  int src = src_csr[p];
  int dst = dst_csr[p];
  uint4 qv = *(const uint4*)(Qb + (size_t)(dst_off + dst) * 256 + ln * 8);
  uint4 kv = *(const uint4*)(KR + (size_t)src * ldk + ln * 8);
  float s = 0.f;
  const unsigned* qa = (const unsigned*)&qv;
  const unsigned* ka = (const unsigned*)&kv;
#pragma unroll
  for (int c = 0; c < 4; ++c) {
    s += bfu2f(qa[c] & 0xffffu) * bfu2f(ka[c] & 0xffffu);
    s += bfu2f(qa[c] >> 16) * bfu2f(ka[c] >> 16);
  }
  s += __shfl_xor(s, 1);
  s += __shfl_xor(s, 2);
  s += __shfl_xor(s, 4);
  int h = ln >> 3;
  if ((ln & 7) == 0)
    SC[(sc_off + p) * 4 + h] = s * prel[h] * 0.125f;
}

// ---- per-node aggregation with FUSED softmax: 2 nodes/wave, 16B loads, GELU --
// SC holds RAW scores; each 8-lane head group computes m and z over its node's
// edge ranges (L1-hot scalar reads), then weights the gather by exp(s-m)/z.
__global__ __launch_bounds__(256) void node_aggr(
    int n, int dst_off,
    const int* __restrict__ rpA, const int* __restrict__ srcA,
    size_t scA, const ushort* __restrict__ VA, int ldA,
    const int* __restrict__ rpB, const int* __restrict__ srcB,
    size_t scB, const ushort* __restrict__ VB, int ldB,
    const float* __restrict__ SC, ushort* __restrict__ AGGb)
{
  int lane = threadIdx.x & 63;
  int sub = lane >> 5;
  int ln = lane & 31;                 // covers cols ln*8 .. ln*8+7 of the 256-col row
  int wid = ((blockIdx.x * blockDim.x + threadIdx.x) >> 6) * 2 + sub;
  if (wid >= n) return;
  int h = ln >> 3;

  int a0 = rpA[wid], a1 = rpA[wid + 1];
  int b0 = 0, b1 = 0;
  if (rpB) { b0 = rpB[wid]; b1 = rpB[wid + 1]; }

  // softmax stats for this (node, head)
  float m = -INFINITY;
  for (int i = a0; i < a1; ++i) m = fmaxf(m, SC[(scA + i) * 4 + h]);
  for (int i = b0; i < b1; ++i) m = fmaxf(m, SC[(scB + i) * 4 + h]);
  float z = 0.f;
  for (int i = a0; i < a1; ++i) z += expf(SC[(scA + i) * 4 + h] - m);
  for (int i = b0; i < b1; ++i) z += expf(SC[(scB + i) * 4 + h] - m);
  float zinv = 1.f / (z + 1e-16f);

  float acc8[8];
#pragma unroll
  for (int c = 0; c < 8; ++c) acc8[c] = 0.f;

  for (int i = a0; i < a1; ++i) {
    float at = expf(SC[(scA + i) * 4 + h] - m) * zinv;
    uint4 v4 = *(const uint4*)(VA + (size_t)srcA[i] * ldA + ln * 8);
    const unsigned* va = (const unsigned*)&v4;
#pragma unroll
    for (int c = 0; c < 4; ++c) {
      acc8[2 * c]     = fmaf(at, bfu2f(va[c] & 0xffffu), acc8[2 * c]);
      acc8[2 * c + 1] = fmaf(at, bfu2f(va[c] >> 16), acc8[2 * c + 1]);
    }
  }
  if (rpB) {
    for (int i = b0; i < b1; ++i) {
      float at = expf(SC[(scB + i) * 4 + h] - m) * zinv;
      uint4 v4 = *(const uint4*)(VB + (size_t)srcB[i] * ldB + ln * 8);
      const unsigned* va = (const unsigned*)&v4;
#pragma unroll
      for (int c = 0; c < 4; ++c) {
        acc8[2 * c]     = fmaf(at, bfu2f(va[c] & 0xffffu), acc8[2 * c]);
        acc8[2 * c + 1] = fmaf(at, bfu2f(va[c] >> 16), acc8[2 * c + 1]);
      }
    }
  }
  ushort o8[8];
#pragma unroll
  for (int c = 0; c < 8; ++c) o8[c] = f2bf(gelu_f(acc8[c]));
  *(uint4*)(AGGb + (size_t)(dst_off + wid) * 256 + ln * 8) = *(const uint4*)o8;
}

// ---------------- pooling ----------------
__global__ void batch_ptr(const int* __restrict__ batch, int n, int* __restrict__ bptr) {
  int b = threadIdx.x;
  if (b > 64) return;
  int lo = 0, hi = n;
  while (lo < hi) { int mid = (lo + hi) >> 1; if (batch[mid] < b) lo = mid + 1; else hi = mid; }
  bptr[b] = lo;
}

__global__ __launch_bounds__(256) void gate_score(
    const float* __restrict__ JK, const float* __restrict__ Wg, const float* __restrict__ bg,
    float* __restrict__ GS, int n)
{
  int w = (blockIdx.x * blockDim.x + threadIdx.x) >> 6;
  int lane = threadIdx.x & 63;
  if (w >= n) return;
  float4 x = *(const float4*)(JK + (size_t)w * 256 + (lane << 2));
  float4 g4 = *(const float4*)(Wg + (lane << 2));
  float s = x.x * g4.x + x.y * g4.y + x.z * g4.z + x.w * g4.w;
#pragma unroll
  for (int off = 32; off >= 1; off >>= 1) s += __shfl_xor(s, off);
  if (lane == 0) GS[w] = s + bg[0];
}

__global__ __launch_bounds__(256) void pool_mz(
    const float* __restrict__ GS, const int* __restrict__ bptr,
    float* __restrict__ MZ)
{
  __shared__ float red[256];
  int b = blockIdx.x;
  int lo = bptr[b], hi = bptr[b + 1];
  int tid = threadIdx.x;
  float m = -INFINITY;
  for (int r = lo + tid; r < hi; r += 256) m = fmaxf(m, GS[r]);
  red[tid] = m; __syncthreads();
  for (int s = 128; s >= 1; s >>= 1) {
    if (tid < s) red[tid] = fmaxf(red[tid], red[tid + s]);
    __syncthreads();
  }
  m = red[0]; __syncthreads();
  float z = 0.f;
  for (int r = lo + tid; r < hi; r += 256) z += expf(GS[r] - m);
  red[tid] = z; __syncthreads();
  for (int s = 128; s >= 1; s >>= 1) {
    if (tid < s) red[tid] += red[tid + s];
    __syncthreads();
  }
  if (tid == 0) { MZ[b * 2] = m; MZ[b * 2 + 1] = 1.f / (red[0] + 1e-16f); }
}

#define NCHUNK 16
__global__ __launch_bounds__(256) void pool_partial(
    const float* __restrict__ JK, const float* __restrict__ GS,
    const int* __restrict__ bptr, const float* __restrict__ MZ,
    float* __restrict__ O784, int colOff)
{
  int b = blockIdx.x;
  int c = blockIdx.y;
  int lo = bptr[b], hi = bptr[b + 1];
  int tid = threadIdx.x;
  float m = MZ[b * 2], zinv = MZ[b * 2 + 1];
  float acc = 0.f;
  for (int r = lo + c; r < hi; r += NCHUNK)
    acc += expf(GS[r] - m) * JK[(size_t)r * 256 + tid];
  if (acc != 0.f)
    atomicAdd(&O784[(size_t)b * 784 + colOff + tid], acc * zinv);
}

__global__ void hy_kernel(
    const float* __restrict__ y, const float* __restrict__ W1, const float* __restrict__ b1,
    const float* __restrict__ W2, const float* __restrict__ b2, float* __restrict__ O784)
{
  int r = threadIdx.x;
  if (r >= 64) return;
  float yv = y[r];
  float h1[16];
#pragma unroll
  for (int j = 0; j < 16; ++j) {
    float v = yv * W1[j] + b1[j];
    h1[j] = v > 0.f ? v : 0.2f * v;
  }
#pragma unroll
  for (int c = 0; c < 16; ++c) {
    float s = b2[c];
#pragma unroll
    for (int j = 0; j < 16; ++j) s += h1[j] * W2[j * 16 + c];
    O784[(size_t)r * 784 + 768 + c] = s;
  }
}

// ---------------- head: one wave per output element, K-parallel reduce ----------------
__global__ __launch_bounds__(256) void dense_wave(
    const float* __restrict__ A, const float* __restrict__ WT,
    const float* __restrict__ bias, float* __restrict__ C,
    int M, int N, int K)
{
  int gw = (blockIdx.x * blockDim.x + threadIdx.x) >> 6;
  int lane = threadIdx.x & 63;
  if (gw >= M * N) return;
  int r = gw / N, c = gw - r * N;
  const float* a = A + (size_t)r * K;
  const float* wv = WT + (size_t)c * K;
  float s = 0.f;
  for (int k = lane; k < K; k += 64) s += a[k] * wv[k];
#pragma unroll
  for (int off = 32; off >= 1; off >>= 1) s += __shfl_xor(s, off);
  if (lane == 0) C[(size_t)r * N + c] = s + (bias ? bias[c] : 0.f);
}

__global__ __launch_bounds__(256) void bn_gelu_wave(
    const float* __restrict__ in, const float* __restrict__ g, const float* __restrict__ be,
    float* __restrict__ out, int C)
{
  int c = (blockIdx.x * blockDim.x + threadIdx.x) >> 6;
  int r = threadIdx.x & 63;
  if (c >= C) return;
  float v = in[(size_t)r * C + c];
  float s = v, q = v * v;
#pragma unroll
  for (int off = 32; off >= 1; off >>= 1) {
    s += __shfl_xor(s, off);
    q += __shfl_xor(q, off);
  }
  float m = s * (1.f / 64.f);
  float var = q * (1.f / 64.f) - m * m;
  float rs = rsqrtf(var + 1e-5f);
  out[(size_t)r * C + c] = gelu_f((v - m) * rs * g[c] + be[c]);
}

extern "C" void kernel_launch(void* const* d_in, const int* in_sizes, int n_in,
                              void* d_out, int out_size, void* d_ws, size_t ws_size,
                              hipStream_t stream)
{
  const float* x_in[3] = {(const float*)d_in[0], (const float*)d_in[1], (const float*)d_in[2]};
  const float* y_base = (const float*)d_in[3];
  const float* W_in = (const float*)d_in[4];
  const float* b_in = (const float*)d_in[5];
  const float* ln_g = (const float*)d_in[6];
  const float* ln_b = (const float*)d_in[7];
  const float* W_kqv = (const float*)d_in[8];
  const float* b_kqv = (const float*)d_in[9];
  const float* W_krel = (const float*)d_in[10];
  const float* W_vrel = (const float*)d_in[11];
  const float* p_rel = (const float*)d_in[12];
  const float* W_out = (const float*)d_in[13];
  const float* b_out = (const float*)d_in[14];
  const float* skipv = (const float*)d_in[15];
  const float* W_jk = (const float*)d_in[16];
  const float* b_jk = (const float*)d_in[17];
  const float* W_gate = (const float*)d_in[18];
  const float* b_gate = (const float*)d_in[19];
  const float* W_y1 = (const float*)d_in[20];
  const float* b_y1 = (const float*)d_in[21];
  const float* W_y2 = (const float*)d_in[22];
  const float* b_y2 = (const float*)d_in[23];
  const float* Wg1 = (const float*)d_in[24];
  const float* bg1 = (const float*)d_in[25];
  const float* g1 = (const float*)d_in[26];
  const float* beta1 = (const float*)d_in[27];
  const float* Wg2 = (const float*)d_in[28];
  const float* bg2 = (const float*)d_in[29];
  const float* g2 = (const float*)d_in[30];
  const float* beta2 = (const float*)d_in[31];
  const float* Wg3 = (const float*)d_in[32];
  const float* bg3 = (const float*)d_in[33];
  const int* eis[4] = {(const int*)d_in[34], (const int*)d_in[35], (const int*)d_in[36], (const int*)d_in[37]};
  const int* batchp[3] = {(const int*)d_in[38], (const int*)d_in[39], (const int*)d_in[40]};

  const int NSs[3] = {NS0, NS1, NS2};
  const int offs[3] = {0, OFF1, OFF2};
  const int NEs[4] = {320000, 320000, 160000, 160000};
  const int stt[4] = {0, 1, 0, 2};
  const size_t scoff[4] = {0, 320000, 640000, 800000};
  const int ndst[4] = {60000, 80000, 30000, 80000};

  float* ws = nullptr;
  if (hipGetSymbolAddress((void**)&ws, HIP_SYMBOL(g_ws)) != hipSuccess || !ws) return;

  const size_t NODE = (size_t)NTOT * 256;
  size_t o = 0;
  float* JKacc = ws + o; o += NODE;
  float* SC = ws + o;    o += (size_t)960000 * 4;
  float* GS = ws + o;    o += (size_t)NTOT;
  float* MZ = ws + o;    o += 128;
  float* O784 = ws + o;  o += (size_t)64 * 784;
  float* BN1 = ws + o;   o += (size_t)64 * 256;
  float* T1 = ws + o;    o += (size_t)64 * 256;
  float* BN2 = ws + o;   o += (size_t)64 * 128;
  float* T2 = ws + o;    o += (size_t)64 * 128;
  float* WT1f = ws + o;  o += (size_t)256 * 784;
  float* WT2f = ws + o;  o += (size_t)128 * 256;
  float* BCMB = ws + o;  o += 16 * 512;
  // bf16 buffers (float units)
  ushort* Qb = (ushort*)(ws + o);      o += NODE / 2;
  ushort* Hb_bf = (ushort*)(ws + o);   o += NODE / 2;
  ushort* X0_bf = (ushort*)(ws + o);   o += NODE / 2;
  ushort* XJK = (ushort*)(ws + o);     o += (size_t)NTOT * 1024 / 2;
  ushort* AGGb = (ushort*)(ws + o);    o += NODE / 2;
  ushort* KVRb = (ushort*)(ws + o);    o += (size_t)250000 * 512 / 2;  // 250k rows x 512 kr|vr
  ushort* Xin_bf = (ushort*)(ws + o);  o += (size_t)NTOT * 128 / 2;
  ushort* WT_in = (ushort*)(ws + o);   o += (size_t)3 * 256 * 128 / 2;
  ushort* WT_kqv = (ushort*)(ws + o);  o += (size_t)12 * 768 * 256 / 2;
  ushort* WB_kqv = (ushort*)(ws + o);  o += (size_t)12 * 256 * 768 / 2;  // non-transposed bf16
  ushort* WT_krel = (ushort*)(ws + o); o += (size_t)16 * 256 * 256 / 2;
  ushort* WT_vrel = (ushort*)(ws + o); o += (size_t)16 * 256 * 256 / 2;
  ushort* WKVb = (ushort*)(ws + o);    o += (size_t)16 * 512 * 256 / 2;  // combined rel wts
  ushort* WT_out = (ushort*)(ws + o);  o += (size_t)12 * 256 * 256 / 2;
  ushort* WT_jk = (ushort*)(ws + o);   o += (size_t)3 * 256 * 1024 / 2;
  // int region (kept last)
  int* ib = (int*)(ws + o);
  size_t io = 0;
  int* rp[4]; int* srcc[4]; int* dstc[4]; int* degc[4];
  for (int e = 0; e < 4; ++e) { rp[e] = ib + io; io += ndst[e] + 1; }
  for (int e = 0; e < 4; ++e) { srcc[e] = ib + io; io += NEs[e]; }
  for (int e = 0; e < 4; ++e) { dstc[e] = ib + io; io += NEs[e]; }
  for (int e = 0; e < 4; ++e) { degc[e] = ib + io; io += ndst[e]; }
  int* bsum = ib + io; io += 257;
  int* bptr3 = ib + io; io += 3 * 65;

  // KVR per-edge-type region offsets (ushort units), rows = NS[stt[e]], ld=512
  const long long KE2[4] = {0, (long long)80000 * 512, (long long)140000 * 512, (long long)220000 * 512};

  auto nrbOf = [](int M) { return (M + 63) / 64; };

  auto gemmS = [&](const ushort* A, int lda, const ushort* W, int ldb,
                   const float* biasBase, float* Cf, int ldc, ushort* Cb, int ldcb,
                   int K, int N, int nseg,
                   const long long* aoff, const long long* woff, const long long* coff,
                   const int* m, const int* bo,
                   const ushort* skH = nullptr, int ldsk = 0,
                   const long long* shoff = nullptr, const int* skidx = nullptr,
                   const float* skv = nullptr) {
    Segs s{};
    s.n = nseg; s.ncb = N / 128;
    s.cum[0] = 0;
    for (int i = 0; i < nseg; ++i) {
      s.cum[i + 1] = s.cum[i] + nrbOf(m[i]);
      s.m[i] = m[i];
      s.aoff[i] = aoff[i]; s.woff[i] = woff[i]; s.coff[i] = coff[i];
      s.shoff[i] = shoff ? shoff[i] : 0;
      s.bo[i] = bo ? bo[i] : 0;
      s.skidx[i] = skidx ? skidx[i] : 0;
    }
    int grid = s.cum[nseg] * s.ncb;
    gemm_seg<<<grid, 256, 0, stream>>>(A, lda, W, ldb, biasBase, Cf, ldc, Cb, ldcb,
                                       K, s, skH, ldsk, skv);
  };

  // ---- weight transpose + bf16 convert ----
  wtrans<<<dim3(4, 8, 3), 256, 0, stream>>>(W_in, WT_in, 128, 256);
  wtrans<<<dim3(8, 24, 12), 256, 0, stream>>>(W_kqv, WT_kqv, 256, 768);
  wtrans<<<dim3(8, 8, 16), 256, 0, stream>>>(W_krel, WT_krel, 256, 256);
  wtrans<<<dim3(8, 8, 16), 256, 0, stream>>>(W_vrel, WT_vrel, 256, 256);
  wtrans<<<dim3(8, 8, 12), 256, 0, stream>>>(W_out, WT_out, 256, 256);
  wtrans<<<dim3(32, 8, 3), 256, 0, stream>>>(W_jk, WT_jk, 1024, 256);
  wtrans_f32<<<dim3(25, 8), 256, 0, stream>>>(Wg1, WT1f, 784, 256);
  wtrans_f32<<<dim3(8, 4), 256, 0, stream>>>(Wg2, WT2f, 256, 128);
  conv_bf16<<<(12 * 256 * 768 / 4 + 255) / 256, 256, 0, stream>>>(W_kqv, WB_kqv, 12 * 256 * 768 / 4);

  for (int i = 0; i < 3; ++i) {
    int n4 = NSs[i] * 128 / 4;
    conv_bf16<<<(n4 + 255) / 256, 256, 0, stream>>>(x_in[i], Xin_bf + (size_t)offs[i] * 128, n4);
  }

  // ---- combined rel weights: per-layer 4-segment dispatches ----
  for (int l = 0; l < 4; ++l) {
    int m4[4] = {256, 256, 256, 256};
    long long a[4], w2[4], c[4];
    for (int e = 0; e < 4; ++e) {
      int le = l * 4 + e;
      a[e] = (long long)le * 65536;
      w2[e] = ((long long)l * 3 + stt[e]) * 256 * 768;
      c[e] = (long long)le * 512 * 256;
    }
    gemmS(WT_krel, 256, WB_kqv, 768, nullptr, nullptr, 256, WKVb, 256, 256, 256,
          4, a, w2, c, m4, nullptr);
    for (int e = 0; e < 4; ++e) {
      int le = l * 4 + e;
      a[e] = (long long)le * 65536;
      w2[e] = ((long long)l * 3 + stt[e]) * 256 * 768 + 512;
      c[e] = (long long)le * 512 * 256 + 256 * 256;
    }
    gemmS(WT_vrel, 256, WB_kqv, 768, nullptr, nullptr, 256, WKVb, 256, 256, 256,
          4, a, w2, c, m4, nullptr);
  }
  bcomb_kernel<<<16, 512, 0, stream>>>(b_kqv, WT_krel, WT_vrel, BCMB);

  // ---- CSR per edge type ----
  for (int e = 0; e < 4; ++e) {
    int n = ndst[e], ne = NEs[e];
    int nb = (n + 1023) / 1024;
    hipMemsetAsync(degc[e], 0, n * sizeof(int), stream);
    csr_hist<<<(ne + 255) / 256, 256, 0, stream>>>(eis[e], ne, degc[e]);
    scan_block<<<nb, 256, 0, stream>>>(degc[e], n, rp[e], bsum);
    scan_bsum<<<1, 1, 0, stream>>>(bsum, nb);
    scan_add<<<(n + 256) / 256, 256, 0, stream>>>(rp[e], n, bsum, nb);
    hipMemsetAsync(degc[e], 0, n * sizeof(int), stream);
    csr_scatter<<<(ne + 255) / 256, 256, 0, stream>>>(eis[e], ne, rp[e], degc[e], srcc[e], dstc[e]);
  }
  for (int i = 0; i < 3; ++i)
    batch_ptr<<<1, 128, 0, stream>>>(batchp[i], NSs[i], bptr3 + i * 65);

  const int m3[3] = {NS0, NS1, NS2};

  // ---- input projection -> X0_bf ----
  {
    long long a[3] = {0, (long long)OFF1 * 128, (long long)OFF2 * 128};
    long long w2[3] = {0, (long long)256 * 128, (long long)2 * 256 * 128};
    long long c[3] = {0, (long long)OFF1 * 256, (long long)OFF2 * 256};
    int bo[3] = {0, 256, 512};
    gemmS(Xin_bf, 128, WT_in, 128, b_in, nullptr, 256, X0_bf, 256, 128, 256,
          3, a, w2, c, m3, bo);
  }

  for (int l = 0; l < 4; ++l) {
    const ushort* lnin = (l == 0) ? X0_bf : (XJK + (size_t)(l - 1) * 256);
    int lnld = (l == 0) ? 256 : 1024;
    ln_kernel<<<(NTOT * 64 + 255) / 256, 256, 0, stream>>>(
        lnin, lnld, ln_g + (size_t)l * 3 * 256, ln_b + (size_t)l * 3 * 256, Hb_bf);

    // q-only projection -> Qb
    {
      long long a[3] = {0, (long long)OFF1 * 256, (long long)OFF2 * 256};
      long long w2[3], c[3] = {0, (long long)OFF1 * 256, (long long)OFF2 * 256};
      int bo[3];
      for (int i = 0; i < 3; ++i) {
        w2[i] = ((long long)l * 3 + i) * 768 * 256 + (long long)256 * 256;  // q rows
        bo[i] = (l * 3 + i) * 768 + 256;
      }
      gemmS(Hb_bf, 256, WT_kqv, 256, b_kqv, nullptr, 256, Qb, 256, 256, 256,
            3, a, w2, c, m3, bo);
    }

    // combined kr|vr: one N=512 dispatch, A = Hb (src-type rows)
    {
      int m4[4] = {NS0, NS1, NS0, NS2};
      long long a[4], w2[4], c[4];
      int bo[4];
      for (int e = 0; e < 4; ++e) {
        a[e] = (long long)offs[stt[e]] * 256;
        w2[e] = ((long long)l * 4 + e) * 512 * 256;
        c[e] = KE2[e];
        bo[e] = (l * 4 + e) * 512;
      }
      gemmS(Hb_bf, 256, WKVb, 256, BCMB, nullptr, 512, KVRb, 512, 256, 512,
            4, a, w2, c, m4, bo);
    }

    for (int e = 0; e < 4; ++e) {
      int dto = (e == 0) ? OFF1 : (e == 2) ? OFF2 : 0;
      edge_scores<<<(NEs[e] * 32 + 255) / 256, 256, 0, stream>>>(
          srcc[e], dstc[e], NEs[e], Qb, dto, KVRb + KE2[e], 512,
          p_rel + ((size_t)l * 4 + e) * 4, SC, scoff[e]);
    }

    // aggregation with fused softmax (type0 <- e1,e3 ; type1 <- e0 ; type2 <- e2)
    node_aggr<<<(NS0 + 7) / 8, 256, 0, stream>>>(
        NS0, 0,
        rp[1], srcc[1], scoff[1], KVRb + KE2[1] + 256, 512,
        rp[3], srcc[3], scoff[3], KVRb + KE2[3] + 256, 512,
        SC, AGGb);
    node_aggr<<<(NS1 + 7) / 8, 256, 0, stream>>>(
        NS1, OFF1,
        rp[0], srcc[0], scoff[0], KVRb + KE2[0] + 256, 512,
        nullptr, nullptr, 0, nullptr, 0,
        SC, AGGb);
    node_aggr<<<(NS2 + 7) / 8, 256, 0, stream>>>(
        NS2, OFF2,
        rp[2], srcc[2], scoff[2], KVRb + KE2[2] + 256, 512,
        nullptr, nullptr, 0, nullptr, 0,
        SC, AGGb);

    // W_out + fused skip -> XJK slot l
    {
      long long a[3] = {0, (long long)OFF1 * 256, (long long)OFF2 * 256};
      long long w2[3], c[3], sh[3] = {0, (long long)OFF1 * 256, (long long)OFF2 * 256};
      int bo[3], sk[3];
      for (int i = 0; i < 3; ++i) {
        w2[i] = ((long long)l * 3 + i) * 256 * 256;
        c[i] = (long long)offs[i] * 1024 + (long long)l * 256;
        bo[i] = (l * 3 + i) * 256;
        sk[i] = l * 3 + i;
      }
      gemmS(AGGb, 256, WT_out, 256, b_out, nullptr, 256, XJK, 1024, 256, 256,
            3, a, w2, c, m3, bo, Hb_bf, 256, sh, sk, skipv);
    }
  }

  // ---- deferred JK: one segmented dispatch, K=1024 ----
  {
    long long a[3] = {0, (long long)OFF1 * 1024, (long long)OFF2 * 1024};
    long long w2[3], c[3] = {0, (long long)OFF1 * 256, (long long)OFF2 * 256};
    int bo[3];
    for (int i = 0; i < 3; ++i) {
      w2[i] = (long long)i * 256 * 1024;
      bo[i] = i * 256;
    }
    gemmS(XJK, 1024, WT_jk, 1024, b_jk, JKacc, 256, nullptr, 256, 1024, 256,
          3, a, w2, c, m3, bo);
  }

  // ---- gated pooling ----
  hipMemsetAsync(O784, 0, (size_t)64 * 784 * sizeof(float), stream);
  for (int i = 0; i < 3; ++i)
    gate_score<<<(NSs[i] * 64 + 255) / 256, 256, 0, stream>>>(
        JKacc + (size_t)offs[i] * 256, W_gate + i * 256, b_gate + i, GS + offs[i], NSs[i]);
  for (int i = 0; i < 3; ++i) {
    pool_mz<<<64, 256, 0, stream>>>(GS + offs[i], bptr3 + i * 65, MZ);
    pool_partial<<<dim3(64, NCHUNK), 256, 0, stream>>>(
        JKacc + (size_t)offs[i] * 256, GS + offs[i], bptr3 + i * 65, MZ, O784, i * 256);
  }

  hy_kernel<<<1, 64, 0, stream>>>(y_base, W_y1, b_y1, W_y2, b_y2, O784);

  // ---- head MLP: wave-parallel ----
  dense_wave<<<(64 * 256 + 3) / 4, 256, 0, stream>>>(O784, WT1f, bg1, BN1, 64, 256, 784);
  bn_gelu_wave<<<(256 + 3) / 4, 256, 0, stream>>>(BN1, g1, beta1, T1, 256);
  dense_wave<<<(64 * 128 + 3) / 4, 256, 0, stream>>>(T1, WT2f, bg2, BN2, 64, 128, 256);
  bn_gelu_wave<<<(128 + 3) / 4, 256, 0, stream>>>(BN2, g2, beta2, T2, 128);
  dense_wave<<<(64 * 1 + 3) / 4, 256, 0, stream>>>(T2, Wg3, bg3, (float*)d_out, 64, 1, 128);
}

// Round 22
// 3769.640 us; speedup vs baseline: 1.0254x; 1.0254x over previous
//
#include <hip/hip_runtime.h>
#include <math.h>

#define NS0 80000
#define NS1 60000
#define NS2 30000
#define NTOT 170000
#define OFF1 80000
#define OFF2 140000

// bulk scratch as device global (harness ws_size too small; allocated at module load)
__device__ float g_ws[372000000];  // ~1.49 GB

typedef __attribute__((ext_vector_type(8))) short bf16x8;
typedef __attribute__((ext_vector_type(4))) float f32x4;

__device__ inline float gelu_f(float x) {
  float x3 = x * x * x;
  return 0.5f * x * (1.0f + tanhf(0.7978845608028654f * (x + 0.044715f * x3)));
}
__device__ inline ushort f2bf(float f) {
  unsigned u = __float_as_uint(f);
  unsigned r = (u + 0x7FFFu + ((u >> 16) & 1u)) >> 16;
  return (ushort)r;
}
__device__ inline float bf2f(ushort u) { return __uint_as_float((unsigned)u << 16); }
__device__ inline float bfu2f(unsigned u16) { return __uint_as_float(u16 << 16); }

// ---- segmented bf16 MFMA GEMM (up to 4 segments) ----
// R17 config: tile 64x128, 4 waves (2x2, each 32x64), BK=32, double-buffered
// LDS prefetch-before-compute, 24KB LDS, XCD-chunked 1D grid.
struct Segs {
  int n, ncb;
  int cum[5];
  int m[4];
  long long aoff[4], woff[4], coff[4], shoff[4];
  int bo[4], skidx[4];
};

__global__ __launch_bounds__(256) void gemm_seg(
    const ushort* __restrict__ A, int lda,
    const ushort* __restrict__ W, int ldb,
    const float* __restrict__ biasBase,
    float* __restrict__ CfBase, int ldc,
    ushort* __restrict__ CbBase, int ldcb,
    int K, Segs segs,
    const ushort* __restrict__ skHBase, int ldsk,
    const float* __restrict__ skvBase)
{
  __shared__ __align__(16) ushort smem[12288];   // 24 KB: staging; epilogue reuses 16 KB
  ushort* Asl = smem;            // 2 bufs x 2048 (64 rows x 32)
  ushort* Bsl = smem + 4096;     // 2 bufs x 4096 (128 rows x 32)

  int total = segs.cum[segs.n] * segs.ncb;
  int b = blockIdx.x;
  int q = total >> 3, r = total & 7;
  int xcd = b & 7, rank = b >> 3;
  int base = (xcd < r) ? xcd * (q + 1) : r * (q + 1) + (xcd - r) * q;
  int work = base + rank;
  int rb = work / segs.ncb;
  int cb = work - rb * segs.ncb;
  int t = 0;
  while (t + 1 < segs.n && rb >= segs.cum[t + 1]) ++t;
  const int row0 = (rb - segs.cum[t]) * 64;
  const int col0 = cb * 128;
  const int M = segs.m[t];
  const ushort* Aseg = A + segs.aoff[t];
  const ushort* Wseg = W + segs.woff[t];

  const int tid = threadIdx.x;
  const int w = tid >> 6, l = tid & 63;
  const int wr = (w >> 1) * 32, wc = (w & 1) * 64;
  const int lr = l >> 2;
  const int lk = (l & 3) * 8;
  const int fr = l & 15;
  const int fk = (l >> 4) * 8;

  f32x4 acc[2][4];
#pragma unroll
  for (int i = 0; i < 2; ++i)
#pragma unroll
    for (int j = 0; j < 4; ++j) acc[i][j] = (f32x4){0.f, 0.f, 0.f, 0.f};

  auto stage = [&](int buf, int k0) {
    {
      const ushort* ga = Aseg + (size_t)(row0 + w * 16 + lr) * lda + k0 + lk;
      __builtin_amdgcn_global_load_lds(
          (const __attribute__((address_space(1))) void*)ga,
          (__attribute__((address_space(3))) void*)&Asl[buf * 2048 + w * 512], 16, 0, 0);
    }
#pragma unroll
    for (int ci = 0; ci < 2; ++ci) {
      int chunk = w * 2 + ci;
      const ushort* gb = Wseg + (size_t)(col0 + chunk * 16 + lr) * ldb + k0 + lk;
      __builtin_amdgcn_global_load_lds(
          (const __attribute__((address_space(1))) void*)gb,
          (__attribute__((address_space(3))) void*)&Bsl[buf * 4096 + chunk * 512], 16, 0, 0);
    }
  };

  const int nk = K >> 5;
  stage(0, 0);
  __syncthreads();
  int cur = 0;
  for (int tt = 0; tt < nk; ++tt) {
    if (tt + 1 < nk) stage(cur ^ 1, (tt + 1) << 5);
    bf16x8 af[2], bfr[4];
#pragma unroll
    for (int i = 0; i < 2; ++i)
      af[i] = *(const bf16x8*)&Asl[cur * 2048 + (wr + i * 16 + fr) * 32 + fk];
#pragma unroll
    for (int j = 0; j < 4; ++j)
      bfr[j] = *(const bf16x8*)&Bsl[cur * 4096 + (wc + j * 16 + fr) * 32 + fk];
#pragma unroll
    for (int i = 0; i < 2; ++i)
#pragma unroll
      for (int j = 0; j < 4; ++j)
        acc[i][j] = __builtin_amdgcn_mfma_f32_16x16x32_bf16(af[i], bfr[j], acc[i][j], 0, 0, 0);
    __syncthreads();
    cur ^= 1;
  }

  const ushort* skH = skHBase ? skHBase + segs.shoff[t] : nullptr;
  float al = 0.f;
  if (skH) al = 1.f / (1.f + __expf(-skvBase[segs.skidx[t]]));
  float* Cf = CfBase ? CfBase + segs.coff[t] : nullptr;
  ushort* Cb = CbBase ? CbBase + segs.coff[t] : nullptr;
  const float* bias = biasBase ? biasBase + segs.bo[t] : nullptr;

#pragma unroll
  for (int j = 0; j < 4; ++j) {
    int lcol = wc + j * 16 + fr;
    int col = col0 + lcol;
    float bv = bias ? bias[col] : 0.f;
#pragma unroll
    for (int i = 0; i < 2; ++i) {
      int lrbase = wr + i * 16 + (l >> 4) * 4;
#pragma unroll
      for (int r2 = 0; r2 < 4; ++r2) {
        int lrow = lrbase + r2;
        int row = row0 + lrow;
        if (row < M) {
          float v = acc[i][j][r2] + bv;
          if (skH) v = al * v + (1.f - al) * bf2f(skH[(size_t)row * ldsk + col]);
          if (Cf) Cf[(size_t)row * ldc + col] = v;
          if (Cb) smem[lrow * 128 + lcol] = f2bf(v);
        }
      }
    }
  }
  if (Cb) {
    __syncthreads();
#pragma unroll
    for (int it = 0; it < 4; ++it) {
      int lrow = it * 16 + (tid >> 4);
      int row = row0 + lrow;
      if (row < M) {
        int lc = (tid & 15) * 8;
        *(bf16x8*)(Cb + (size_t)row * ldcb + col0 + lc) =
            *(const bf16x8*)&smem[lrow * 128 + lc];
      }
    }
  }
}

// transpose f32 [K][N] -> bf16 [N][K], batched over blockIdx.z
__global__ __launch_bounds__(256) void wtrans(
    const float* __restrict__ src, ushort* __restrict__ dst, int K, int N)
{
  __shared__ float t[32][33];
  size_t zo = (size_t)blockIdx.z * K * N;
  int kb = blockIdx.x * 32, nb = blockIdx.y * 32;
  int tx = threadIdx.x & 31, ty = threadIdx.x >> 5;
#pragma unroll
  for (int r = 0; r < 32; r += 8) {
    int k = kb + ty + r, n = nb + tx;
    if (k < K && n < N) t[ty + r][tx] = src[zo + (size_t)k * N + n];
  }
  __syncthreads();
#pragma unroll
  for (int r = 0; r < 32; r += 8) {
    int n = nb + ty + r, k = kb + tx;
    if (n < N && k < K) dst[zo + (size_t)n * K + k] = f2bf(t[tx][ty + r]);
  }
}

__global__ __launch_bounds__(256) void wtrans_f32(
    const float* __restrict__ src, float* __restrict__ dst, int K, int N)
{
  __shared__ float t[32][33];
  int kb = blockIdx.x * 32, nb = blockIdx.y * 32;
  int tx = threadIdx.x & 31, ty = threadIdx.x >> 5;
#pragma unroll
  for (int r = 0; r < 32; r += 8) {
    int k = kb + ty + r, n = nb + tx;
    if (k < K && n < N) t[ty + r][tx] = src[(size_t)k * N + n];
  }
  __syncthreads();
#pragma unroll
  for (int r = 0; r < 32; r += 8) {
    int n = nb + ty + r, k = kb + tx;
    if (n < N && k < K) dst[(size_t)n * K + k] = t[tx][ty + r];
  }
}

__global__ void conv_bf16(const float* __restrict__ in, ushort* __restrict__ out, int n4) {
  int i = blockIdx.x * blockDim.x + threadIdx.x;
  if (i >= n4) return;
  float4 v = *(const float4*)(in + (size_t)i * 4);
  ushort4 o;
  o.x = f2bf(v.x); o.y = f2bf(v.y); o.z = f2bf(v.z); o.w = f2bf(v.w);
  *(ushort4*)(out + (size_t)i * 4) = o;
}

// combined rel bias: BCMB[(l,e)][0:256]=b_k@W_krel, [256:512]=b_v@W_vrel
__global__ __launch_bounds__(512) void bcomb_kernel(
    const float* __restrict__ b_kqv,
    const ushort* __restrict__ WT_krel, const ushort* __restrict__ WT_vrel,
    float* __restrict__ BCMB)
{
  int le = blockIdx.x;            // l*4+e
  int l = le >> 2, e = le & 3;
  int ti = (e == 0) ? 0 : (e == 1) ? 1 : (e == 2) ? 0 : 2;
  int j = threadIdx.x;
  const float* bb = b_kqv + ((size_t)l * 3 + ti) * 768 + ((j < 256) ? 0 : 512);
  const ushort* wrow = ((j < 256) ? WT_krel : WT_vrel) +
                       (size_t)le * 65536 + (size_t)(j & 255) * 256;
  float s = 0.f;
  for (int o2 = 0; o2 < 256; ++o2) s += bb[o2] * bf2f(wrow[o2]);
  BCMB[(size_t)le * 512 + j] = s;
}

// ---------------- LayerNorm: bf16 in (ld param), bf16 out ----------------
__global__ __launch_bounds__(256) void ln_kernel(
    const ushort* __restrict__ X, int ldx,
    const float* __restrict__ g, const float* __restrict__ b,
    ushort* __restrict__ Hbf)
{
  int w = (blockIdx.x * blockDim.x + threadIdx.x) >> 6;
  int lane = threadIdx.x & 63;
  if (w >= NTOT) return;
  int type = (w < NS0) ? 0 : (w < OFF2 ? 1 : 2);
  ushort4 xb = *(const ushort4*)(X + (size_t)w * ldx + (lane << 2));
  float x0 = bf2f(xb.x), x1 = bf2f(xb.y), x2 = bf2f(xb.z), x3 = bf2f(xb.w);
  float s = x0 + x1 + x2 + x3;
  float q = x0 * x0 + x1 * x1 + x2 * x2 + x3 * x3;
#pragma unroll
  for (int off = 32; off >= 1; off >>= 1) {
    s += __shfl_xor(s, off);
    q += __shfl_xor(q, off);
  }
  float m = s * (1.f / 256.f);
  float var = q * (1.f / 256.f) - m * m;
  float rs = rsqrtf(var + 1e-5f);
  float4 gg = *(const float4*)(g + type * 256 + (lane << 2));
  float4 bb = *(const float4*)(b + type * 256 + (lane << 2));
  ushort4 ob;
  ob.x = f2bf((x0 - m) * rs * gg.x + bb.x);
  ob.y = f2bf((x1 - m) * rs * gg.y + bb.y);
  ob.z = f2bf((x2 - m) * rs * gg.z + bb.z);
  ob.w = f2bf((x3 - m) * rs * gg.w + bb.w);
  *(ushort4*)(Hbf + (size_t)w * 256 + (lane << 2)) = ob;
}

// ---------------- CSR build ----------------
__global__ void csr_hist(const int* __restrict__ ei, int ne, int* __restrict__ deg) {
  int t = blockIdx.x * blockDim.x + threadIdx.x;
  if (t < ne) atomicAdd(&deg[ei[ne + t]], 1);
}
__global__ __launch_bounds__(256) void scan_block(
    const int* __restrict__ in, int n, int* __restrict__ out, int* __restrict__ bsum)
{
  __shared__ int sdata[256];
  int tid = threadIdx.x;
  int base = blockIdx.x * 1024 + tid * 4;
  int v[4]; int s = 0;
#pragma unroll
  for (int j = 0; j < 4; ++j) {
    int x = (base + j < n) ? in[base + j] : 0;
    v[j] = s; s += x;
  }
  sdata[tid] = s;
  __syncthreads();
  int own = s;
  for (int off = 1; off < 256; off <<= 1) {
    int u = (tid >= off) ? sdata[tid - off] : 0;
    __syncthreads();
    sdata[tid] += u;
    __syncthreads();
  }
  int thrExcl = sdata[tid] - own;
#pragma unroll
  for (int j = 0; j < 4; ++j)
    if (base + j < n) out[base + j] = thrExcl + v[j];
  if (tid == 255) bsum[blockIdx.x] = sdata[255];
}
__global__ void scan_bsum(int* __restrict__ bsum, int nb) {
  if (threadIdx.x == 0 && blockIdx.x == 0) {
    int r = 0;
    for (int b = 0; b < nb; ++b) { int t = bsum[b]; bsum[b] = r; r += t; }
    bsum[nb] = r;
  }
}
__global__ void scan_add(int* __restrict__ out, int n, const int* __restrict__ bsum, int nb) {
  int i = blockIdx.x * blockDim.x + threadIdx.x;
  if (i < n) out[i] += bsum[i >> 10];
  else if (i == n) out[n] = bsum[nb];
}
__global__ void csr_scatter(const int* __restrict__ ei, int ne,
                            const int* __restrict__ rowptr, int* __restrict__ cur,
                            int* __restrict__ src_csr, int* __restrict__ dst_csr) {
  int t = blockIdx.x * blockDim.x + threadIdx.x;
  if (t >= ne) return;
  int d = ei[ne + t];
  int pos = rowptr[d] + atomicAdd(&cur[d], 1);
  src_csr[pos] = ei[t];
  dst_csr[pos] = d;
}

// ---------------- edge scores: 2 edges per wave, 16B loads ----------------
__global__ __launch_bounds__(256) void edge_scores(
    const int* __restrict__ src_csr, const int* __restrict__ dst_csr, int ne,
    const ushort* __restrict__ Qb, int dst_off,
    const ushort* __restrict__ KR, int ldk,
    const float* __restrict__ prel,
    float* __restrict__ SC, size_t sc_off)
{
  int lane = threadIdx.x & 63;
  int sub = lane >> 5;
  int ln = lane & 31;
  int p = ((blockIdx.x * blockDim.x + threadIdx.x) >> 6) * 2 + sub;
  if (p >= ne) return;
  int src = src_csr[p];
  int dst = dst_csr[p];
  uint4 qv = *(const uint4*)(Qb + (size_t)(dst_off + dst) * 256 + ln * 8);
  uint4 kv = *(const uint4*)(KR + (size_t)src * ldk + ln * 8);
  float s = 0.f;
  const unsigned* qa = (const unsigned*)&qv;
  const unsigned* ka = (const unsigned*)&kv;
#pragma unroll
  for (int c = 0; c < 4; ++c) {
    s += bfu2f(qa[c] & 0xffffu) * bfu2f(ka[c] & 0xffffu);
    s += bfu2f(qa[c] >> 16) * bfu2f(ka[c] >> 16);
  }
  s += __shfl_xor(s, 1);
  s += __shfl_xor(s, 2);
  s += __shfl_xor(s, 4);
  int h = ln >> 3;
  if ((ln & 7) == 0)
    SC[(sc_off + p) * 4 + h] = s * prel[h] * 0.125f;
}

// ---------------- per-node softmax over CONTIGUOUS CSR score ranges ----------------
__global__ __launch_bounds__(256) void node_softmax(
    int n,
    const int* __restrict__ rpA, size_t scA,
    const int* __restrict__ rpB, size_t scB,
    float* __restrict__ SC)
{
  int gid = blockIdx.x * blockDim.x + threadIdx.x;
  if (gid >= n * 4) return;
  int nd = gid >> 2, h = gid & 3;
  int a0 = rpA[nd], a1 = rpA[nd + 1];
  int b0 = 0, b1 = 0;
  if (rpB) { b0 = rpB[nd]; b1 = rpB[nd + 1]; }
  if (a1 == a0 && b1 == b0) return;
  float m = -INFINITY;
  for (int i = a0; i < a1; ++i) m = fmaxf(m, SC[(scA + i) * 4 + h]);
  for (int i = b0; i < b1; ++i) m = fmaxf(m, SC[(scB + i) * 4 + h]);
  float z = 0.f;
  for (int i = a0; i < a1; ++i) {
    size_t p = (scA + i) * 4 + h;
    float e = expf(SC[p] - m); SC[p] = e; z += e;
  }
  for (int i = b0; i < b1; ++i) {
    size_t p = (scB + i) * 4 + h;
    float e = expf(SC[p] - m); SC[p] = e; z += e;
  }
  float inv = 1.f / (z + 1e-16f);
  for (int i = a0; i < a1; ++i) SC[(scA + i) * 4 + h] *= inv;
  for (int i = b0; i < b1; ++i) SC[(scB + i) * 4 + h] *= inv;
}

// ---------------- per-node aggregation: 2 nodes/wave, 16B loads, GELU fused ----
__global__ __launch_bounds__(256) void node_aggr(
    int n, int dst_off,
    const int* __restrict__ rpA, const int* __restrict__ srcA,
    size_t scA, const ushort* __restrict__ VA, int ldA,
    const int* __restrict__ rpB, const int* __restrict__ srcB,
    size_t scB, const ushort* __restrict__ VB, int ldB,
    const float* __restrict__ SC, ushort* __restrict__ AGGb)
{
  int lane = threadIdx.x & 63;
  int sub = lane >> 5;
  int ln = lane & 31;                 // covers cols ln*8 .. ln*8+7 of the 256-col row
  int wid = ((blockIdx.x * blockDim.x + threadIdx.x) >> 6) * 2 + sub;
  if (wid >= n) return;
  int h = ln >> 3;
  float acc8[8];
#pragma unroll
  for (int c = 0; c < 8; ++c) acc8[c] = 0.f;

  int a0 = rpA[wid], a1 = rpA[wid + 1];
  for (int i = a0; i < a1; ++i) {
    float at = SC[(scA + i) * 4 + h];
    uint4 v4 = *(const uint4*)(VA + (size_t)srcA[i] * ldA + ln * 8);
    const unsigned* va = (const unsigned*)&v4;
#pragma unroll
    for (int c = 0; c < 4; ++c) {
      acc8[2 * c]     = fmaf(at, bfu2f(va[c] & 0xffffu), acc8[2 * c]);
      acc8[2 * c + 1] = fmaf(at, bfu2f(va[c] >> 16), acc8[2 * c + 1]);
    }
  }
  if (rpB) {
    int b0 = rpB[wid], b1 = rpB[wid + 1];
    for (int i = b0; i < b1; ++i) {
      float at = SC[(scB + i) * 4 + h];
      uint4 v4 = *(const uint4*)(VB + (size_t)srcB[i] * ldB + ln * 8);
      const unsigned* va = (const unsigned*)&v4;
#pragma unroll
      for (int c = 0; c < 4; ++c) {
        acc8[2 * c]     = fmaf(at, bfu2f(va[c] & 0xffffu), acc8[2 * c]);
        acc8[2 * c + 1] = fmaf(at, bfu2f(va[c] >> 16), acc8[2 * c + 1]);
      }
    }
  }
  ushort o8[8];
#pragma unroll
  for (int c = 0; c < 8; ++c) o8[c] = f2bf(gelu_f(acc8[c]));
  *(uint4*)(AGGb + (size_t)(dst_off + wid) * 256 + ln * 8) = *(const uint4*)o8;
}

// ---------------- pooling ----------------
__global__ void batch_ptr(const int* __restrict__ batch, int n, int* __restrict__ bptr) {
  int b = threadIdx.x;
  if (b > 64) return;
  int lo = 0, hi = n;
  while (lo < hi) { int mid = (lo + hi) >> 1; if (batch[mid] < b) lo = mid + 1; else hi = mid; }
  bptr[b] = lo;
}

__global__ __launch_bounds__(256) void gate_score(
    const float* __restrict__ JK, const float* __restrict__ Wg, const float* __restrict__ bg,
    float* __restrict__ GS, int n)
{
  int w = (blockIdx.x * blockDim.x + threadIdx.x) >> 6;
  int lane = threadIdx.x & 63;
  if (w >= n) return;
  float4 x = *(const float4*)(JK + (size_t)w * 256 + (lane << 2));
  float4 g4 = *(const float4*)(Wg + (lane << 2));
  float s = x.x * g4.x + x.y * g4.y + x.z * g4.z + x.w * g4.w;
#pragma unroll
  for (int off = 32; off >= 1; off >>= 1) s += __shfl_xor(s, off);
  if (lane == 0) GS[w] = s + bg[0];
}

__global__ __launch_bounds__(256) void pool_mz(
    const float* __restrict__ GS, const int* __restrict__ bptr,
    float* __restrict__ MZ)
{
  __shared__ float red[256];
  int b = blockIdx.x;
  int lo = bptr[b], hi = bptr[b + 1];
  int tid = threadIdx.x;
  float m = -INFINITY;
  for (int r = lo + tid; r < hi; r += 256) m = fmaxf(m, GS[r]);
  red[tid] = m; __syncthreads();
  for (int s = 128; s >= 1; s >>= 1) {
    if (tid < s) red[tid] = fmaxf(red[tid], red[tid + s]);
    __syncthreads();
  }
  m = red[0]; __syncthreads();
  float z = 0.f;
  for (int r = lo + tid; r < hi; r += 256) z += expf(GS[r] - m);
  red[tid] = z; __syncthreads();
  for (int s = 128; s >= 1; s >>= 1) {
    if (tid < s) red[tid] += red[tid + s];
    __syncthreads();
  }
  if (tid == 0) { MZ[b * 2] = m; MZ[b * 2 + 1] = 1.f / (red[0] + 1e-16f); }
}

#define NCHUNK 16
__global__ __launch_bounds__(256) void pool_partial(
    const float* __restrict__ JK, const float* __restrict__ GS,
    const int* __restrict__ bptr, const float* __restrict__ MZ,
    float* __restrict__ O784, int colOff)
{
  int b = blockIdx.x;
  int c = blockIdx.y;
  int lo = bptr[b], hi = bptr[b + 1];
  int tid = threadIdx.x;
  float m = MZ[b * 2], zinv = MZ[b * 2 + 1];
  float acc = 0.f;
  for (int r = lo + c; r < hi; r += NCHUNK)
    acc += expf(GS[r] - m) * JK[(size_t)r * 256 + tid];
  if (acc != 0.f)
    atomicAdd(&O784[(size_t)b * 784 + colOff + tid], acc * zinv);
}

__global__ void hy_kernel(
    const float* __restrict__ y, const float* __restrict__ W1, const float* __restrict__ b1,
    const float* __restrict__ W2, const float* __restrict__ b2, float* __restrict__ O784)
{
  int r = threadIdx.x;
  if (r >= 64) return;
  float yv = y[r];
  float h1[16];
#pragma unroll
  for (int j = 0; j < 16; ++j) {
    float v = yv * W1[j] + b1[j];
    h1[j] = v > 0.f ? v : 0.2f * v;
  }
#pragma unroll
  for (int c = 0; c < 16; ++c) {
    float s = b2[c];
#pragma unroll
    for (int j = 0; j < 16; ++j) s += h1[j] * W2[j * 16 + c];
    O784[(size_t)r * 784 + 768 + c] = s;
  }
}

// ---------------- head: one wave per output element, K-parallel reduce ----------------
__global__ __launch_bounds__(256) void dense_wave(
    const float* __restrict__ A, const float* __restrict__ WT,
    const float* __restrict__ bias, float* __restrict__ C,
    int M, int N, int K)
{
  int gw = (blockIdx.x * blockDim.x + threadIdx.x) >> 6;
  int lane = threadIdx.x & 63;
  if (gw >= M * N) return;
  int r = gw / N, c = gw - r * N;
  const float* a = A + (size_t)r * K;
  const float* wv = WT + (size_t)c * K;
  float s = 0.f;
  for (int k = lane; k < K; k += 64) s += a[k] * wv[k];
#pragma unroll
  for (int off = 32; off >= 1; off >>= 1) s += __shfl_xor(s, off);
  if (lane == 0) C[(size_t)r * N + c] = s + (bias ? bias[c] : 0.f);
}

__global__ __launch_bounds__(256) void bn_gelu_wave(
    const float* __restrict__ in, const float* __restrict__ g, const float* __restrict__ be,
    float* __restrict__ out, int C)
{
  int c = (blockIdx.x * blockDim.x + threadIdx.x) >> 6;
  int r = threadIdx.x & 63;
  if (c >= C) return;
  float v = in[(size_t)r * C + c];
  float s = v, q = v * v;
#pragma unroll
  for (int off = 32; off >= 1; off >>= 1) {
    s += __shfl_xor(s, off);
    q += __shfl_xor(q, off);
  }
  float m = s * (1.f / 64.f);
  float var = q * (1.f / 64.f) - m * m;
  float rs = rsqrtf(var + 1e-5f);
  out[(size_t)r * C + c] = gelu_f((v - m) * rs * g[c] + be[c]);
}

extern "C" void kernel_launch(void* const* d_in, const int* in_sizes, int n_in,
                              void* d_out, int out_size, void* d_ws, size_t ws_size,
                              hipStream_t stream)
{
  const float* x_in[3] = {(const float*)d_in[0], (const float*)d_in[1], (const float*)d_in[2]};
  const float* y_base = (const float*)d_in[3];
  const float* W_in = (const float*)d_in[4];
  const float* b_in = (const float*)d_in[5];
  const float* ln_g = (const float*)d_in[6];
  const float* ln_b = (const float*)d_in[7];
  const float* W_kqv = (const float*)d_in[8];
  const float* b_kqv = (const float*)d_in[9];
  const float* W_krel = (const float*)d_in[10];
  const float* W_vrel = (const float*)d_in[11];
  const float* p_rel = (const float*)d_in[12];
  const float* W_out = (const float*)d_in[13];
  const float* b_out = (const float*)d_in[14];
  const float* skipv = (const float*)d_in[15];
  const float* W_jk = (const float*)d_in[16];
  const float* b_jk = (const float*)d_in[17];
  const float* W_gate = (const float*)d_in[18];
  const float* b_gate = (const float*)d_in[19];
  const float* W_y1 = (const float*)d_in[20];
  const float* b_y1 = (const float*)d_in[21];
  const float* W_y2 = (const float*)d_in[22];
  const float* b_y2 = (const float*)d_in[23];
  const float* Wg1 = (const float*)d_in[24];
  const float* bg1 = (const float*)d_in[25];
  const float* g1 = (const float*)d_in[26];
  const float* beta1 = (const float*)d_in[27];
  const float* Wg2 = (const float*)d_in[28];
  const float* bg2 = (const float*)d_in[29];
  const float* g2 = (const float*)d_in[30];
  const float* beta2 = (const float*)d_in[31];
  const float* Wg3 = (const float*)d_in[32];
  const float* bg3 = (const float*)d_in[33];
  const int* eis[4] = {(const int*)d_in[34], (const int*)d_in[35], (const int*)d_in[36], (const int*)d_in[37]};
  const int* batchp[3] = {(const int*)d_in[38], (const int*)d_in[39], (const int*)d_in[40]};

  const int NSs[3] = {NS0, NS1, NS2};
  const int offs[3] = {0, OFF1, OFF2};
  const int NEs[4] = {320000, 320000, 160000, 160000};
  const int stt[4] = {0, 1, 0, 2};
  const size_t scoff[4] = {0, 320000, 640000, 800000};
  const int ndst[4] = {60000, 80000, 30000, 80000};

  float* ws = nullptr;
  if (hipGetSymbolAddress((void**)&ws, HIP_SYMBOL(g_ws)) != hipSuccess || !ws) return;

  const size_t NODE = (size_t)NTOT * 256;
  size_t o = 0;
  float* JKacc = ws + o; o += NODE;
  float* SC = ws + o;    o += (size_t)960000 * 4;
  float* GS = ws + o;    o += (size_t)NTOT;
  float* MZ = ws + o;    o += 128;
  float* O784 = ws + o;  o += (size_t)64 * 784;
  float* BN1 = ws + o;   o += (size_t)64 * 256;
  float* T1 = ws + o;    o += (size_t)64 * 256;
  float* BN2 = ws + o;   o += (size_t)64 * 128;
  float* T2 = ws + o;    o += (size_t)64 * 128;
  float* WT1f = ws + o;  o += (size_t)256 * 784;
  float* WT2f = ws + o;  o += (size_t)128 * 256;
  float* BCMB = ws + o;  o += 16 * 512;
  // bf16 buffers (float units)
  ushort* Qb = (ushort*)(ws + o);      o += NODE / 2;
  ushort* Hb_bf = (ushort*)(ws + o);   o += NODE / 2;
  ushort* X0_bf = (ushort*)(ws + o);   o += NODE / 2;
  ushort* XJK = (ushort*)(ws + o);     o += (size_t)NTOT * 1024 / 2;
  ushort* AGGb = (ushort*)(ws + o);    o += NODE / 2;
  ushort* KVRb = (ushort*)(ws + o);    o += (size_t)250000 * 512 / 2;  // 250k rows x 512 kr|vr
  ushort* Xin_bf = (ushort*)(ws + o);  o += (size_t)NTOT * 128 / 2;
  ushort* WT_in = (ushort*)(ws + o);   o += (size_t)3 * 256 * 128 / 2;
  ushort* WT_kqv = (ushort*)(ws + o);  o += (size_t)12 * 768 * 256 / 2;
  ushort* WB_kqv = (ushort*)(ws + o);  o += (size_t)12 * 256 * 768 / 2;  // non-transposed bf16
  ushort* WT_krel = (ushort*)(ws + o); o += (size_t)16 * 256 * 256 / 2;
  ushort* WT_vrel = (ushort*)(ws + o); o += (size_t)16 * 256 * 256 / 2;
  ushort* WKVb = (ushort*)(ws + o);    o += (size_t)16 * 512 * 256 / 2;  // combined rel wts
  ushort* WT_out = (ushort*)(ws + o);  o += (size_t)12 * 256 * 256 / 2;
  ushort* WT_jk = (ushort*)(ws + o);   o += (size_t)3 * 256 * 1024 / 2;
  // int region (kept last)
  int* ib = (int*)(ws + o);
  size_t io = 0;
  int* rp[4]; int* srcc[4]; int* dstc[4]; int* degc[4];
  for (int e = 0; e < 4; ++e) { rp[e] = ib + io; io += ndst[e] + 1; }
  for (int e = 0; e < 4; ++e) { srcc[e] = ib + io; io += NEs[e]; }
  for (int e = 0; e < 4; ++e) { dstc[e] = ib + io; io += NEs[e]; }
  for (int e = 0; e < 4; ++e) { degc[e] = ib + io; io += ndst[e]; }
  int* bsum = ib + io; io += 257;
  int* bptr3 = ib + io; io += 3 * 65;

  // KVR per-edge-type region offsets (ushort units), rows = NS[stt[e]], ld=512
  const long long KE2[4] = {0, (long long)80000 * 512, (long long)140000 * 512, (long long)220000 * 512};

  auto nrbOf = [](int M) { return (M + 63) / 64; };

  auto gemmS = [&](const ushort* A, int lda, const ushort* W, int ldb,
                   const float* biasBase, float* Cf, int ldc, ushort* Cb, int ldcb,
                   int K, int N, int nseg,
                   const long long* aoff, const long long* woff, const long long* coff,
                   const int* m, const int* bo,
                   const ushort* skH = nullptr, int ldsk = 0,
                   const long long* shoff = nullptr, const int* skidx = nullptr,
                   const float* skv = nullptr) {
    Segs s{};
    s.n = nseg; s.ncb = N / 128;
    s.cum[0] = 0;
    for (int i = 0; i < nseg; ++i) {
      s.cum[i + 1] = s.cum[i] + nrbOf(m[i]);
      s.m[i] = m[i];
      s.aoff[i] = aoff[i]; s.woff[i] = woff[i]; s.coff[i] = coff[i];
      s.shoff[i] = shoff ? shoff[i] : 0;
      s.bo[i] = bo ? bo[i] : 0;
      s.skidx[i] = skidx ? skidx[i] : 0;
    }
    int grid = s.cum[nseg] * s.ncb;
    gemm_seg<<<grid, 256, 0, stream>>>(A, lda, W, ldb, biasBase, Cf, ldc, Cb, ldcb,
                                       K, s, skH, ldsk, skv);
  };

  // ---- weight transpose + bf16 convert ----
  wtrans<<<dim3(4, 8, 3), 256, 0, stream>>>(W_in, WT_in, 128, 256);
  wtrans<<<dim3(8, 24, 12), 256, 0, stream>>>(W_kqv, WT_kqv, 256, 768);
  wtrans<<<dim3(8, 8, 16), 256, 0, stream>>>(W_krel, WT_krel, 256, 256);
  wtrans<<<dim3(8, 8, 16), 256, 0, stream>>>(W_vrel, WT_vrel, 256, 256);
  wtrans<<<dim3(8, 8, 12), 256, 0, stream>>>(W_out, WT_out, 256, 256);
  wtrans<<<dim3(32, 8, 3), 256, 0, stream>>>(W_jk, WT_jk, 1024, 256);
  wtrans_f32<<<dim3(25, 8), 256, 0, stream>>>(Wg1, WT1f, 784, 256);
  wtrans_f32<<<dim3(8, 4), 256, 0, stream>>>(Wg2, WT2f, 256, 128);
  conv_bf16<<<(12 * 256 * 768 / 4 + 255) / 256, 256, 0, stream>>>(W_kqv, WB_kqv, 12 * 256 * 768 / 4);

  for (int i = 0; i < 3; ++i) {
    int n4 = NSs[i] * 128 / 4;
    conv_bf16<<<(n4 + 255) / 256, 256, 0, stream>>>(x_in[i], Xin_bf + (size_t)offs[i] * 128, n4);
  }

  // ---- combined rel weights: per-layer 4-segment dispatches ----
  for (int l = 0; l < 4; ++l) {
    int m4[4] = {256, 256, 256, 256};
    long long a[4], w2[4], c[4];
    for (int e = 0; e < 4; ++e) {
      int le = l * 4 + e;
      a[e] = (long long)le * 65536;
      w2[e] = ((long long)l * 3 + stt[e]) * 256 * 768;
      c[e] = (long long)le * 512 * 256;
    }
    gemmS(WT_krel, 256, WB_kqv, 768, nullptr, nullptr, 256, WKVb, 256, 256, 256,
          4, a, w2, c, m4, nullptr);
    for (int e = 0; e < 4; ++e) {
      int le = l * 4 + e;
      a[e] = (long long)le * 65536;
      w2[e] = ((long long)l * 3 + stt[e]) * 256 * 768 + 512;
      c[e] = (long long)le * 512 * 256 + 256 * 256;
    }
    gemmS(WT_vrel, 256, WB_kqv, 768, nullptr, nullptr, 256, WKVb, 256, 256, 256,
          4, a, w2, c, m4, nullptr);
  }
  bcomb_kernel<<<16, 512, 0, stream>>>(b_kqv, WT_krel, WT_vrel, BCMB);

  // ---- CSR per edge type ----
  for (int e = 0; e < 4; ++e) {
    int n = ndst[e], ne = NEs[e];
    int nb = (n + 1023) / 1024;
    hipMemsetAsync(degc[e], 0, n * sizeof(int), stream);
    csr_hist<<<(ne + 255) / 256, 256, 0, stream>>>(eis[e], ne, degc[e]);
    scan_block<<<nb, 256, 0, stream>>>(degc[e], n, rp[e], bsum);
    scan_bsum<<<1, 1, 0, stream>>>(bsum, nb);
    scan_add<<<(n + 256) / 256, 256, 0, stream>>>(rp[e], n, bsum, nb);
    hipMemsetAsync(degc[e], 0, n * sizeof(int), stream);
    csr_scatter<<<(ne + 255) / 256, 256, 0, stream>>>(eis[e], ne, rp[e], degc[e], srcc[e], dstc[e]);
  }
  for (int i = 0; i < 3; ++i)
    batch_ptr<<<1, 128, 0, stream>>>(batchp[i], NSs[i], bptr3 + i * 65);

  const int m3[3] = {NS0, NS1, NS2};

  // ---- input projection -> X0_bf ----
  {
    long long a[3] = {0, (long long)OFF1 * 128, (long long)OFF2 * 128};
    long long w2[3] = {0, (long long)256 * 128, (long long)2 * 256 * 128};
    long long c[3] = {0, (long long)OFF1 * 256, (long long)OFF2 * 256};
    int bo[3] = {0, 256, 512};
    gemmS(Xin_bf, 128, WT_in, 128, b_in, nullptr, 256, X0_bf, 256, 128, 256,
          3, a, w2, c, m3, bo);
  }

  for (int l = 0; l < 4; ++l) {
    const ushort* lnin = (l == 0) ? X0_bf : (XJK + (size_t)(l - 1) * 256);
    int lnld = (l == 0) ? 256 : 1024;
    ln_kernel<<<(NTOT * 64 + 255) / 256, 256, 0, stream>>>(
        lnin, lnld, ln_g + (size_t)l * 3 * 256, ln_b + (size_t)l * 3 * 256, Hb_bf);

    // q-only projection -> Qb
    {
      long long a[3] = {0, (long long)OFF1 * 256, (long long)OFF2 * 256};
      long long w2[3], c[3] = {0, (long long)OFF1 * 256, (long long)OFF2 * 256};
      int bo[3];
      for (int i = 0; i < 3; ++i) {
        w2[i] = ((long long)l * 3 + i) * 768 * 256 + (long long)256 * 256;  // q rows
        bo[i] = (l * 3 + i) * 768 + 256;
      }
      gemmS(Hb_bf, 256, WT_kqv, 256, b_kqv, nullptr, 256, Qb, 256, 256, 256,
            3, a, w2, c, m3, bo);
    }

    // combined kr|vr: one N=512 dispatch, A = Hb (src-type rows)
    {
      int m4[4] = {NS0, NS1, NS0, NS2};
      long long a[4], w2[4], c[4];
      int bo[4];
      for (int e = 0; e < 4; ++e) {
        a[e] = (long long)offs[stt[e]] * 256;
        w2[e] = ((long long)l * 4 + e) * 512 * 256;
        c[e] = KE2[e];
        bo[e] = (l * 4 + e) * 512;
      }
      gemmS(Hb_bf, 256, WKVb, 256, BCMB, nullptr, 512, KVRb, 512, 256, 512,
            4, a, w2, c, m4, bo);
    }

    for (int e = 0; e < 4; ++e) {
      int dto = (e == 0) ? OFF1 : (e == 2) ? OFF2 : 0;
      edge_scores<<<(NEs[e] * 32 + 255) / 256, 256, 0, stream>>>(
          srcc[e], dstc[e], NEs[e], Qb, dto, KVRb + KE2[e], 512,
          p_rel + ((size_t)l * 4 + e) * 4, SC, scoff[e]);
    }

    node_softmax<<<(NS0 * 4 + 255) / 256, 256, 0, stream>>>(
        NS0, rp[1], scoff[1], rp[3], scoff[3], SC);
    node_softmax<<<(NS1 * 4 + 255) / 256, 256, 0, stream>>>(
        NS1, rp[0], scoff[0], nullptr, 0, SC);
    node_softmax<<<(NS2 * 4 + 255) / 256, 256, 0, stream>>>(
        NS2, rp[2], scoff[2], nullptr, 0, SC);

    node_aggr<<<(NS0 + 7) / 8, 256, 0, stream>>>(
        NS0, 0,
        rp[1], srcc[1], scoff[1], KVRb + KE2[1] + 256, 512,
        rp[3], srcc[3], scoff[3], KVRb + KE2[3] + 256, 512,
        SC, AGGb);
    node_aggr<<<(NS1 + 7) / 8, 256, 0, stream>>>(
        NS1, OFF1,
        rp[0], srcc[0], scoff[0], KVRb + KE2[0] + 256, 512,
        nullptr, nullptr, 0, nullptr, 0,
        SC, AGGb);
    node_aggr<<<(NS2 + 7) / 8, 256, 0, stream>>>(
        NS2, OFF2,
        rp[2], srcc[2], scoff[2], KVRb + KE2[2] + 256, 512,
        nullptr, nullptr, 0, nullptr, 0,
        SC, AGGb);

    // W_out + fused skip -> XJK slot l
    {
      long long a[3] = {0, (long long)OFF1 * 256, (long long)OFF2 * 256};
      long long w2[3], c[3], sh[3] = {0, (long long)OFF1 * 256, (long long)OFF2 * 256};
      int bo[3], sk[3];
      for (int i = 0; i < 3; ++i) {
        w2[i] = ((long long)l * 3 + i) * 256 * 256;
        c[i] = (long long)offs[i] * 1024 + (long long)l * 256;
        bo[i] = (l * 3 + i) * 256;
        sk[i] = l * 3 + i;
      }
      gemmS(AGGb, 256, WT_out, 256, b_out, nullptr, 256, XJK, 1024, 256, 256,
            3, a, w2, c, m3, bo, Hb_bf, 256, sh, sk, skipv);
    }
  }

  // ---- deferred JK: one segmented dispatch, K=1024 ----
  {
    long long a[3] = {0, (long long)OFF1 * 1024, (long long)OFF2 * 1024};
    long long w2[3], c[3] = {0, (long long)OFF1 * 256, (long long)OFF2 * 256};
    int bo[3];
    for (int i = 0; i < 3; ++i) {
      w2[i] = (long long)i * 256 * 1024;
      bo[i] = i * 256;
    }
    gemmS(XJK, 1024, WT_jk, 1024, b_jk, JKacc, 256, nullptr, 256, 1024, 256,
          3, a, w2, c, m3, bo);
  }

  // ---- gated pooling ----
  hipMemsetAsync(O784, 0, (size_t)64 * 784 * sizeof(float), stream);
  for (int i = 0; i < 3; ++i)
    gate_score<<<(NSs[i] * 64 + 255) / 256, 256, 0, stream>>>(
        JKacc + (size_t)offs[i] * 256, W_gate + i * 256, b_gate + i, GS + offs[i], NSs[i]);
  for (int i = 0; i < 3; ++i) {
    pool_mz<<<64, 256, 0, stream>>>(GS + offs[i], bptr3 + i * 65, MZ);
    pool_partial<<<dim3(64, NCHUNK), 256, 0, stream>>>(
        JKacc + (size_t)offs[i] * 256, GS + offs[i], bptr3 + i * 65, MZ, O784, i * 256);
  }

  hy_kernel<<<1, 64, 0, stream>>>(y_base, W_y1, b_y1, W_y2, b_y2, O784);

  // ---- head MLP: wave-parallel ----
  dense_wave<<<(64 * 256 + 3) / 4, 256, 0, stream>>>(O784, WT1f, bg1, BN1, 64, 256, 784);
  bn_gelu_wave<<<(256 + 3) / 4, 256, 0, stream>>>(BN1, g1, beta1, T1, 256);
  dense_wave<<<(64 * 128 + 3) / 4, 256, 0, stream>>>(T1, WT2f, bg2, BN2, 64, 128, 256);
  bn_gelu_wave<<<(128 + 3) / 4, 256, 0, stream>>>(BN2, g2, beta2, T2, 128);
  dense_wave<<<(64 * 1 + 3) / 4, 256, 0, stream>>>(T2, Wg3, bg3, (float*)d_out, 64, 1, 128);
}